// Round 1
// baseline (346.079 us; speedup 1.0000x reference)
//
#include <hip/hip_runtime.h>
#include <hip/hip_bf16.h>
#include <stdint.h>

// ---------- types ----------
typedef __bf16  bf16x8 __attribute__((ext_vector_type(8)));
typedef short   s16x8  __attribute__((ext_vector_type(8)));
typedef int     i32x4  __attribute__((ext_vector_type(4)));
typedef float   f32x4  __attribute__((ext_vector_type(4)));

union Frag { s16x8 s; bf16x8 b; i32x4 i; };

static __device__ __forceinline__ short f2bf(float f) {
    union { float f; unsigned u; } v; v.f = f;
    unsigned r = (v.u + 0x7FFFu + ((v.u >> 16) & 1u)) >> 16;   // RNE
    return (short)r;
}
static __device__ __forceinline__ float bf2f(short s) {
    union { unsigned u; float f; } v; v.u = ((unsigned)(unsigned short)s) << 16;
    return v.f;
}
static __device__ __forceinline__ float fast_rcp(float x) { return __builtin_amdgcn_rcpf(x); }
static __device__ __forceinline__ float sigm(float x) { return fast_rcp(1.0f + __expf(-x)); }
static __device__ __forceinline__ float tanh_fast(float x) {
    float e = __expf(-2.0f * x);
    return (1.0f - e) * fast_rcp(1.0f + e);
}
static __device__ __forceinline__ f32x4 mfma16(bf16x8 a, bf16x8 b, f32x4 c) {
    return __builtin_amdgcn_mfma_f32_16x16x32_bf16(a, b, c, 0, 0, 0);
}

#define GLDS(gp, lp) __builtin_amdgcn_global_load_lds( \
    (const __attribute__((address_space(1))) void*)(gp), \
    (__attribute__((address_space(3))) void*)(lp), 16, 0, 0)

// Constants
#define TT 128
#define BB 2048
#define HH 64
#define FF 128
#define AA 15
#define CH 8                  // y staging chunk (steps), double-buffered
#define LOGITS_OFF 0
#define VF_OFF   3932160
#define HT_OFF   4194304
#define CT_OFF   4325376

// y_sw swizzled: per 16-row tile: 1024 bf16 = [kf(2)][lane(64)][8] (A-frag order)

// ============================ encoder ============================
__global__ __launch_bounds__(256) void enc_kernel(
    const float* __restrict__ x, const float* __restrict__ W1, const float* __restrict__ b1,
    const float* __restrict__ W2, const float* __restrict__ b2, short* __restrict__ y_sw)
{
    __shared__ short w1t[64][136];
    __shared__ short w2t[64][72];
    __shared__ short c1buf[4][16][72];
    __shared__ short ybuf[4][16][72];

    const int tid  = threadIdx.x;
    const int lane = tid & 63;
    const int w    = tid >> 6;
    const int c    = lane & 15;
    const int q    = lane >> 4;

    for (int i = tid; i < 128*64; i += 256) { int k = i >> 6, n = i & 63; w1t[n][k] = f2bf(W1[i]); }
    for (int i = tid; i < 64*64;  i += 256) { int k = i >> 6, n = i & 63; w2t[n][k] = f2bf(W2[i]); }

    float b1v[4], b2v[4];
#pragma unroll
    for (int ct = 0; ct < 4; ++ct) { b1v[ct] = b1[16*ct + c]; b2v[ct] = b2[16*ct + c]; }
    __syncthreads();

    for (int it = 0; it < 4; ++it) {
        const int wt = it*4096 + blockIdx.x*4 + w;
        const int r0 = wt * 16;
        Frag af[4];
#pragma unroll
        for (int kf = 0; kf < 4; ++kf) {
            const float* xp = x + (size_t)(r0 + c)*FF + 32*kf + 8*q;
            f32x4 x0 = *(const f32x4*)xp;
            f32x4 x1 = *(const f32x4*)(xp + 4);
#pragma unroll
            for (int jj = 0; jj < 4; ++jj) { af[kf].s[jj] = f2bf(x0[jj]); af[kf].s[4+jj] = f2bf(x1[jj]); }
        }
        f32x4 acc[4];
#pragma unroll
        for (int ct = 0; ct < 4; ++ct) acc[ct] = (f32x4){b1v[ct], b1v[ct], b1v[ct], b1v[ct]};
#pragma unroll
        for (int kf = 0; kf < 4; ++kf)
#pragma unroll
            for (int ct = 0; ct < 4; ++ct) {
                Frag bf; bf.s = *(const s16x8*)&w1t[16*ct + c][32*kf + 8*q];
                acc[ct] = mfma16(af[kf].b, bf.b, acc[ct]);
            }
#pragma unroll
        for (int ct = 0; ct < 4; ++ct)
#pragma unroll
            for (int i = 0; i < 4; ++i)
                c1buf[w][4*q + i][16*ct + c] = f2bf(tanh_fast(acc[ct][i]));
        Frag a2[2];
#pragma unroll
        for (int kf = 0; kf < 2; ++kf) a2[kf].s = *(const s16x8*)&c1buf[w][c][32*kf + 8*q];
        f32x4 acc2[4];
#pragma unroll
        for (int ct = 0; ct < 4; ++ct) acc2[ct] = (f32x4){b2v[ct], b2v[ct], b2v[ct], b2v[ct]};
#pragma unroll
        for (int kf = 0; kf < 2; ++kf)
#pragma unroll
            for (int ct = 0; ct < 4; ++ct) {
                Frag bf; bf.s = *(const s16x8*)&w2t[16*ct + c][32*kf + 8*q];
                acc2[ct] = mfma16(a2[kf].b, bf.b, acc2[ct]);
            }
#pragma unroll
        for (int ct = 0; ct < 4; ++ct)
#pragma unroll
            for (int i = 0; i < 4; ++i)
                ybuf[w][4*q + i][16*ct + c] = f2bf(tanh_fast(acc2[ct][i]));
#pragma unroll
        for (int kf = 0; kf < 2; ++kf) {
            s16x8 yv = *(const s16x8*)&ybuf[w][c][32*kf + 8*q];
            *(s16x8*)(y_sw + (size_t)wt*1024 + kf*512 + lane*8) = yv;
        }
    }
}

// ============================ LSTM scan (uniform i-split waves) ============================
// 128 blocks x 512 thr. 8 symmetric waves: pair (w, w+4) owns col-slice 16*(w&3);
// both compute the full 4-gate accumulator (Whh MFMA duplicated, cheap), each does
// elementwise for 2 of the 4 accumulator rows. gy[t+1] lives in registers (no gybuf
// LDS round-trip). Heads write straight to global on a rotating duty wave.
__global__ __launch_bounds__(512, 1) void scan_kernel(
    const short* __restrict__ y_sw, const float* __restrict__ done,
    const float* __restrict__ h0, const float* __restrict__ c0,
    const float* __restrict__ Wih, const float* __restrict__ bih,
    const float* __restrict__ Whh, const float* __restrict__ bhh,
    const float* __restrict__ Wa, const float* __restrict__ ba,
    const float* __restrict__ Wc, const float* __restrict__ bc,
    float* __restrict__ out_logits, float* __restrict__ out_vf,
    float* __restrict__ hT_out, float* __restrict__ cT_out)
{
    __shared__ short ybuf[2][CH][1024];     // 32 KB  staged y (A-frag order), dbl-buf
    __shared__ short zbuf[2][16][72];       // 4.6 KB unmasked h (for heads/hT)
    __shared__ short hbuf[2][16][72];       // 4.6 KB masked h (scan state)
    __shared__ float dbuf[TT+1][16];        // 8.3 KB done, +zero row 128

    const int tid  = threadIdx.x;
    const int lane = tid & 63;
    const int w    = tid >> 6;      // 0..7
    const int wc   = w & 3;         // col-tile
    const int wh   = w >> 2;        // 0 -> rows i=0,1 ; 1 -> rows i=2,3
    const int c    = lane & 15;
    const int q    = lane >> 4;
    const int blk  = blockIdx.x;
    const int b0   = blk * 16;
    const int jcol = 16*wc + c;

    // ---------------- per-wave register state ----------------
    Frag  wf[4][2];      // Whh B-frags
    Frag  wfi[4][2];     // Wih B-frags
    Frag  hwf[2];        // head B-frags
    float biasv[4];
    float hbv;
    float cst0, cst1;    // c state (2 rows per wave)

#pragma unroll
    for (int a = 0; a < 4; ++a) {
        const int col = 64*a + jcol;
        biasv[a] = bih[col] + bhh[col];
#pragma unroll
        for (int kf = 0; kf < 2; ++kf) {
            const float* wp = Whh + (size_t)col*HH + 32*kf + 8*q;
            f32x4 w0 = *(const f32x4*)wp;
            f32x4 w1 = *(const f32x4*)(wp + 4);
#pragma unroll
            for (int jj = 0; jj < 4; ++jj) { wf[a][kf].s[jj] = f2bf(w0[jj]); wf[a][kf].s[4+jj] = f2bf(w1[jj]); }
            const float* vp = Wih + (size_t)col*HH + 32*kf + 8*q;
            f32x4 v0 = *(const f32x4*)vp;
            f32x4 v1 = *(const f32x4*)(vp + 4);
#pragma unroll
            for (int jj = 0; jj < 4; ++jj) { wfi[a][kf].s[jj] = f2bf(v0[jj]); wfi[a][kf].s[4+jj] = f2bf(v1[jj]); }
        }
    }
#pragma unroll
    for (int kf = 0; kf < 2; ++kf)
#pragma unroll
        for (int jj = 0; jj < 8; ++jj) {
            int k = 32*kf + 8*q + jj;
            hwf[kf].s[jj] = f2bf((c < 15) ? Wa[k*AA + c] : Wc[k]);
        }
    hbv = (c < 15) ? ba[c] : bc[0];

    // ---- stage done (all 128 steps; 1 GLDS per wave) + y chunk 0 (2 per wave)
    {
        const float* gp = done + (size_t)(16*w + (lane >> 2))*BB + b0 + 4*(lane & 3);
        GLDS(gp, &dbuf[16*w][0]);
    }
#pragma unroll
    for (int half = 0; half < 2; ++half) {
        const short* gp = y_sw + ((size_t)w*128 + blk)*1024 + half*512 + lane*8;
        GLDS(gp, &ybuf[0][w][half*512]);
    }
    if (tid < 16) dbuf[TT][tid] = 0.0f;       // mask row for t=127 write-side
    __builtin_amdgcn_s_waitcnt(0x0F70);       // vmcnt(0)
    __syncthreads();   // A: dbuf + ybuf[0] visible

    // c state init (masked by done[0]); rows 4q + 2*wh + {0,1}
    {
        float d0 = dbuf[0][4*q + 2*wh + 0];
        float d1 = dbuf[0][4*q + 2*wh + 1];
        float cv0 = c0[(size_t)(b0 + 4*q + 2*wh + 0)*HH + jcol];
        float cv1 = c0[(size_t)(b0 + 4*q + 2*wh + 1)*HH + jcol];
        cst0 = (d0 != 0.0f) ? 0.0f : cv0;
        cst1 = (d1 != 0.0f) ? 0.0f : cv1;
    }
    // h0 (masked) -> hbuf[0]
    if (tid < 256) {
        int mm = tid & 15, j4 = tid >> 4;
        float dm = dbuf[0][mm];
        f32x4 hv = *(const f32x4*)(h0 + (size_t)(b0 + mm)*HH + 4*j4);
#pragma unroll
        for (int ii = 0; ii < 4; ++ii)
            hbuf[0][mm][4*j4 + ii] = (dm != 0.0f) ? (short)0 : f2bf(hv[ii]);
    }
    // gy[0] = bias + y0@Wih^T  (registers)
    f32x4 gyr[4];
    {
        Frag yc0, yc1;
        yc0.s = *(const s16x8*)&ybuf[0][0][lane*8];
        yc1.s = *(const s16x8*)&ybuf[0][0][512 + lane*8];
#pragma unroll
        for (int a = 0; a < 4; ++a) {
            f32x4 g = (f32x4){biasv[a], biasv[a], biasv[a], biasv[a]};
            g = mfma16(yc0.b, wfi[a][0].b, g);
            g = mfma16(yc1.b, wfi[a][1].b, g);
            gyr[a] = g;
        }
    }
    __syncthreads();   // B: hbuf[0] ready

    for (int t = 0; t < TT; ++t) {
        const int cur = t & 1;
        // ---- h frags (issue early)
        Frag hf0, hf1;
        hf0.s = *(const s16x8*)&hbuf[cur][c][8*q];
        hf1.s = *(const s16x8*)&hbuf[cur][c][32 + 8*q];
        // ---- stage y chunk (t/8)+1
        if ((t & 7) == 0 && t < 120) {
            const int k = (t >> 3) + 1;
#pragma unroll
            for (int half = 0; half < 2; ++half) {
                const short* gp = y_sw + ((size_t)(8*k + w)*128 + blk)*1024 + half*512 + lane*8;
                GLDS(gp, &ybuf[k & 1][w][half*512]);
            }
        }
        // ---- y frags for t+1
        Frag yc0, yc1;
        if (t < TT-1) {
            const int tn = t + 1;
            yc0.s = *(const s16x8*)&ybuf[(tn >> 3) & 1][tn & 7][lane*8];
            yc1.s = *(const s16x8*)&ybuf[(tn >> 3) & 1][tn & 7][512 + lane*8];
        }
        // ---- gates: accumulate h@Whh^T into gy (bit-exact order: bias, y-MFMAs, h-MFMAs)
#pragma unroll
        for (int a = 0; a < 4; ++a) {
            gyr[a] = mfma16(hf0.b, wf[a][0].b, gyr[a]);
            gyr[a] = mfma16(hf1.b, wf[a][1].b, gyr[a]);
        }
        const float dn0 = dbuf[t+1][4*q + 2*wh + 0];   // mask for NEXT step
        const float dn1 = dbuf[t+1][4*q + 2*wh + 1];
        // ---- elementwise for this wave's 2 rows (compile-time row index)
#define ELEM(CSTV, I, DN) {                                             \
            float gi = gyr[0][I], gf = gyr[1][I], gg = gyr[2][I], go = gyr[3][I]; \
            float cn = sigm(gf)*CSTV + sigm(gi)*tanh_fast(gg);          \
            float hv = sigm(go)*tanh_fast(cn);                          \
            short zb = f2bf(hv);                                        \
            zbuf[cur][4*q + I][jcol] = zb;                              \
            const bool d = ((DN) != 0.0f);                              \
            CSTV = d ? 0.0f : cn;                                       \
            hbuf[cur ^ 1][4*q + I][jcol] = d ? (short)0 : zb; }
        if (wh == 0) { ELEM(cst0, 0, dn0) ELEM(cst1, 1, dn1) }
        else         { ELEM(cst0, 2, dn0) ELEM(cst1, 3, dn1) }
#undef ELEM
        // ---- gy refill for t+1 (independent of this step's chain)
        if (t < TT-1) {
#pragma unroll
            for (int a = 0; a < 4; ++a) {
                f32x4 g = (f32x4){biasv[a], biasv[a], biasv[a], biasv[a]};
                g = mfma16(yc0.b, wfi[a][0].b, g);
                g = mfma16(yc1.b, wfi[a][1].b, g);
                gyr[a] = g;
            }
        }
        // ---- drain staging off the path BEFORE head stores are issued
        if ((t & 7) == 6) __builtin_amdgcn_s_waitcnt(0x0F70);
        // ---- head duty (rotating wave) for z[t-1] -> global (fire-and-forget)
        if (t >= 1 && w == ((t-1) & 7)) {
            const int tp = t - 1;
            Frag zf0, zf1;
            zf0.s = *(const s16x8*)&zbuf[tp & 1][c][8*q];
            zf1.s = *(const s16x8*)&zbuf[tp & 1][c][32 + 8*q];
            f32x4 ha = (f32x4){hbv, hbv, hbv, hbv};
            ha = mfma16(zf0.b, hwf[0].b, ha);
            ha = mfma16(zf1.b, hwf[1].b, ha);
#pragma unroll
            for (int i = 0; i < 4; ++i) {
                const size_t row = (size_t)tp*BB + b0 + 4*q + i;
                if (c < 15) out_logits[row*AA + c] = ha[i];
                else        out_vf[row] = ha[i];
            }
        }
        __syncthreads();
    }

    // ---------------- epilogue ----------------
    if (w == 7) {                              // head for z[127]
        Frag zf0, zf1;
        zf0.s = *(const s16x8*)&zbuf[1][c][8*q];
        zf1.s = *(const s16x8*)&zbuf[1][c][32 + 8*q];
        f32x4 ha = (f32x4){hbv, hbv, hbv, hbv};
        ha = mfma16(zf0.b, hwf[0].b, ha);
        ha = mfma16(zf1.b, hwf[1].b, ha);
#pragma unroll
        for (int i = 0; i < 4; ++i) {
            const size_t row = (size_t)127*BB + b0 + 4*q + i;
            if (c < 15) out_logits[row*AA + c] = ha[i];
            else        out_vf[row] = ha[i];
        }
    }
    if (tid < 256) {                           // hT = z127
        int mm = tid & 15, j4 = tid >> 4;
        f32x4 hv;
#pragma unroll
        for (int ii = 0; ii < 4; ++ii) hv[ii] = bf2f(zbuf[1][mm][4*j4 + ii]);
        *(f32x4*)(hT_out + (size_t)(b0 + mm)*HH + 4*j4) = hv;
    }
    cT_out[(size_t)(b0 + 4*q + 2*wh + 0)*HH + jcol] = cst0;
    cT_out[(size_t)(b0 + 4*q + 2*wh + 1)*HH + jcol] = cst1;
}

// ============================ launch ============================
extern "C" void kernel_launch(void* const* d_in, const int* in_sizes, int n_in,
                              void* d_out, int out_size, void* d_ws, size_t ws_size,
                              hipStream_t stream) {
    const float* x    = (const float*)d_in[0];
    const float* done = (const float*)d_in[1];
    const float* h0   = (const float*)d_in[2];
    const float* c0   = (const float*)d_in[3];
    const float* W1   = (const float*)d_in[4];
    const float* b1   = (const float*)d_in[5];
    const float* W2   = (const float*)d_in[6];
    const float* b2   = (const float*)d_in[7];
    const float* Wih  = (const float*)d_in[8];
    const float* bih  = (const float*)d_in[9];
    const float* Whh  = (const float*)d_in[10];
    const float* bhh  = (const float*)d_in[11];
    const float* Wa   = (const float*)d_in[12];
    const float* ba   = (const float*)d_in[13];
    const float* Wc   = (const float*)d_in[14];
    const float* bc   = (const float*)d_in[15];
    float* out = (float*)d_out;

    short* y_sw = (short*)d_ws;     // 32 MiB swizzled encoder output

    enc_kernel<<<1024, 256, 0, stream>>>(x, W1, b1, W2, b2, y_sw);
    scan_kernel<<<128, 512, 0, stream>>>(y_sw, done, h0, c0, Wih, bih, Whh, bhh,
                                         Wa, ba, Wc, bc,
                                         out + LOGITS_OFF, out + VF_OFF,
                                         out + HT_OFF, out + CT_OFF);
}

// Round 2
// 322.004 us; speedup vs baseline: 1.0748x; 1.0748x over previous
//
#include <hip/hip_runtime.h>
#include <hip/hip_bf16.h>
#include <stdint.h>

// ---------- types ----------
typedef __bf16  bf16x8 __attribute__((ext_vector_type(8)));
typedef short   s16x8  __attribute__((ext_vector_type(8)));
typedef int     i32x4  __attribute__((ext_vector_type(4)));
typedef float   f32x4  __attribute__((ext_vector_type(4)));

union Frag { s16x8 s; bf16x8 b; i32x4 i; };

static __device__ __forceinline__ short f2bf(float f) {
    union { float f; unsigned u; } v; v.f = f;
    unsigned r = (v.u + 0x7FFFu + ((v.u >> 16) & 1u)) >> 16;   // RNE
    return (short)r;
}
static __device__ __forceinline__ float bf2f(short s) {
    union { unsigned u; float f; } v; v.u = ((unsigned)(unsigned short)s) << 16;
    return v.f;
}
static __device__ __forceinline__ float fast_rcp(float x) { return __builtin_amdgcn_rcpf(x); }
static __device__ __forceinline__ float sigm(float x) { return fast_rcp(1.0f + __expf(-x)); }
static __device__ __forceinline__ float tanh_fast(float x) {
    float e = __expf(-2.0f * x);
    return (1.0f - e) * fast_rcp(1.0f + e);
}
static __device__ __forceinline__ f32x4 mfma16(bf16x8 a, bf16x8 b, f32x4 c) {
    return __builtin_amdgcn_mfma_f32_16x16x32_bf16(a, b, c, 0, 0, 0);
}

// Barrier that does NOT drain vmcnt: LDS writes made visible (lgkmcnt(0)),
// but global stores / global_load_lds stay in flight across the barrier.
// (__syncthreads emits s_waitcnt vmcnt(0) lgkmcnt(0) — that vmem drain was
//  the per-step stall; staging/stores are drained once per 8 steps instead.)
static __device__ __forceinline__ void block_sync_lds() {
    asm volatile("s_waitcnt lgkmcnt(0)\n\ts_barrier" ::: "memory");
}

#define GLDS(gp, lp) __builtin_amdgcn_global_load_lds( \
    (const __attribute__((address_space(1))) void*)(gp), \
    (__attribute__((address_space(3))) void*)(lp), 16, 0, 0)

// Constants
#define TT 128
#define BB 2048
#define HH 64
#define FF 128
#define AA 15
#define CH 8                  // y staging chunk (steps), double-buffered
#define LOGITS_OFF 0
#define VF_OFF   3932160
#define HT_OFF   4194304
#define CT_OFF   4325376

// y_sw swizzled: per 16-row tile: 1024 bf16 = [kf(2)][lane(64)][8] (A-frag order)

// ============================ encoder ============================
__global__ __launch_bounds__(256) void enc_kernel(
    const float* __restrict__ x, const float* __restrict__ W1, const float* __restrict__ b1,
    const float* __restrict__ W2, const float* __restrict__ b2, short* __restrict__ y_sw)
{
    __shared__ short w1t[64][136];
    __shared__ short w2t[64][72];
    __shared__ short c1buf[4][16][72];
    __shared__ short ybuf[4][16][72];

    const int tid  = threadIdx.x;
    const int lane = tid & 63;
    const int w    = tid >> 6;
    const int c    = lane & 15;
    const int q    = lane >> 4;

    for (int i = tid; i < 128*64; i += 256) { int k = i >> 6, n = i & 63; w1t[n][k] = f2bf(W1[i]); }
    for (int i = tid; i < 64*64;  i += 256) { int k = i >> 6, n = i & 63; w2t[n][k] = f2bf(W2[i]); }

    float b1v[4], b2v[4];
#pragma unroll
    for (int ct = 0; ct < 4; ++ct) { b1v[ct] = b1[16*ct + c]; b2v[ct] = b2[16*ct + c]; }
    __syncthreads();

    for (int it = 0; it < 4; ++it) {
        const int wt = it*4096 + blockIdx.x*4 + w;
        const int r0 = wt * 16;
        Frag af[4];
#pragma unroll
        for (int kf = 0; kf < 4; ++kf) {
            const float* xp = x + (size_t)(r0 + c)*FF + 32*kf + 8*q;
            f32x4 x0 = *(const f32x4*)xp;
            f32x4 x1 = *(const f32x4*)(xp + 4);
#pragma unroll
            for (int jj = 0; jj < 4; ++jj) { af[kf].s[jj] = f2bf(x0[jj]); af[kf].s[4+jj] = f2bf(x1[jj]); }
        }
        f32x4 acc[4];
#pragma unroll
        for (int ct = 0; ct < 4; ++ct) acc[ct] = (f32x4){b1v[ct], b1v[ct], b1v[ct], b1v[ct]};
#pragma unroll
        for (int kf = 0; kf < 4; ++kf)
#pragma unroll
            for (int ct = 0; ct < 4; ++ct) {
                Frag bf; bf.s = *(const s16x8*)&w1t[16*ct + c][32*kf + 8*q];
                acc[ct] = mfma16(af[kf].b, bf.b, acc[ct]);
            }
#pragma unroll
        for (int ct = 0; ct < 4; ++ct)
#pragma unroll
            for (int i = 0; i < 4; ++i)
                c1buf[w][4*q + i][16*ct + c] = f2bf(tanh_fast(acc[ct][i]));
        Frag a2[2];
#pragma unroll
        for (int kf = 0; kf < 2; ++kf) a2[kf].s = *(const s16x8*)&c1buf[w][c][32*kf + 8*q];
        f32x4 acc2[4];
#pragma unroll
        for (int ct = 0; ct < 4; ++ct) acc2[ct] = (f32x4){b2v[ct], b2v[ct], b2v[ct], b2v[ct]};
#pragma unroll
        for (int kf = 0; kf < 2; ++kf)
#pragma unroll
            for (int ct = 0; ct < 4; ++ct) {
                Frag bf; bf.s = *(const s16x8*)&w2t[16*ct + c][32*kf + 8*q];
                acc2[ct] = mfma16(a2[kf].b, bf.b, acc2[ct]);
            }
#pragma unroll
        for (int ct = 0; ct < 4; ++ct)
#pragma unroll
            for (int i = 0; i < 4; ++i)
                ybuf[w][4*q + i][16*ct + c] = f2bf(tanh_fast(acc2[ct][i]));
#pragma unroll
        for (int kf = 0; kf < 2; ++kf) {
            s16x8 yv = *(const s16x8*)&ybuf[w][c][32*kf + 8*q];
            *(s16x8*)(y_sw + (size_t)wt*1024 + kf*512 + lane*8) = yv;
        }
    }
}

// ============================ LSTM scan (specialized waves) ============================
// 128 blocks x 512 thr. Waves 0-3: critical path (h@Whh MFMA + elementwise,
// write-side done-masking). Waves 4-7: helpers (gy[t+1]=bias+y@Wih precompute,
// y chunk staging via global_load_lds, heads for z[t-1], output flush).
// In-loop barrier is lgkmcnt-only (block_sync_lds) so helper vmem stays in
// flight across steps; helpers drain their own vmcnt once per 8 steps (t&7==6).
__global__ __launch_bounds__(512, 1) void scan_kernel(
    const short* __restrict__ y_sw, const float* __restrict__ done,
    const float* __restrict__ h0, const float* __restrict__ c0,
    const float* __restrict__ Wih, const float* __restrict__ bih,
    const float* __restrict__ Whh, const float* __restrict__ bhh,
    const float* __restrict__ Wa, const float* __restrict__ ba,
    const float* __restrict__ Wc, const float* __restrict__ bc,
    float* __restrict__ out_logits, float* __restrict__ out_vf,
    float* __restrict__ hT_out, float* __restrict__ cT_out)
{
    __shared__ short ybuf[2][CH][1024];     // 32 KB  staged y (A-frag order), dbl-buf
    __shared__ float gybuf[2][4][4][256];   // 32 KB  gy = bias + y@Wih^T, dbl-buf
    __shared__ float obuf[2][CH][16][16];   // 16 KB  head outputs, dbl-buf by chunk
    __shared__ short zbuf[2][16][72];       // 4.6 KB unmasked h (for heads/hT)
    __shared__ short hbuf[2][16][72];       // 4.6 KB masked h (scan state)
    __shared__ float dbuf[TT+1][16];        // 8.3 KB done, +zero row 128

    const int tid  = threadIdx.x;
    const int lane = tid & 63;
    const int w    = tid >> 6;
    const int c    = lane & 15;
    const int q    = lane >> 4;
    const int blk  = blockIdx.x;
    const int b0   = blk * 16;
    const bool crit = (w < 4);
    const int hw   = w - 4;

    // ---------------- per-role register state ----------------
    Frag  wf[4][2];      // crit: Whh B-frags        helper: Wih B-frags
    float biasv[4];      // helper only
    Frag  hwf[2];        // helper: head B-frags
    float hbv = 0.f;     // helper: head bias
    float cst[4];        // crit: c state

    if (crit) {
        const int jcol = 16*w + c;
#pragma unroll
        for (int a = 0; a < 4; ++a) {
            const int col = 64*a + jcol;
#pragma unroll
            for (int kf = 0; kf < 2; ++kf) {
                const float* wp = Whh + (size_t)col*HH + 32*kf + 8*q;
                f32x4 w0 = *(const f32x4*)wp;
                f32x4 w1 = *(const f32x4*)(wp + 4);
#pragma unroll
                for (int jj = 0; jj < 4; ++jj) { wf[a][kf].s[jj] = f2bf(w0[jj]); wf[a][kf].s[4+jj] = f2bf(w1[jj]); }
            }
        }
    } else {
        const int jcolh = 16*hw + c;
#pragma unroll
        for (int a = 0; a < 4; ++a) {
            const int col = 64*a + jcolh;
            biasv[a] = bih[col] + bhh[col];
#pragma unroll
            for (int kf = 0; kf < 2; ++kf) {
                const float* wp = Wih + (size_t)col*HH + 32*kf + 8*q;
                f32x4 w0 = *(const f32x4*)wp;
                f32x4 w1 = *(const f32x4*)(wp + 4);
#pragma unroll
                for (int jj = 0; jj < 4; ++jj) { wf[a][kf].s[jj] = f2bf(w0[jj]); wf[a][kf].s[4+jj] = f2bf(w1[jj]); }
            }
        }
#pragma unroll
        for (int kf = 0; kf < 2; ++kf)
#pragma unroll
            for (int jj = 0; jj < 8; ++jj) {
                int k = 32*kf + 8*q + jj;
                hwf[kf].s[jj] = f2bf((c < 15) ? Wa[k*AA + c] : Wc[k]);
            }
        hbv = (c < 15) ? ba[c] : bc[0];
        // ---- stage done (all 128 steps) + y chunk 0
#pragma unroll
        for (int i = 0; i < 2; ++i) {
            int j = hw*2 + i;   // 0..7 -> steps 16j..16j+15
            const float* gp = done + (size_t)(16*j + (lane >> 2))*BB + b0 + 4*(lane & 3);
            GLDS(gp, &dbuf[16*j][0]);
        }
#pragma unroll
        for (int i = 0; i < 4; ++i) {
            int idx = hw*4 + i, ss = idx >> 1, half = idx & 1;
            const short* gp = y_sw + ((size_t)ss*128 + blk)*1024 + half*512 + lane*8;
            GLDS(gp, &ybuf[0][ss][half*512]);
        }
        __builtin_amdgcn_s_waitcnt(0x0F70);   // vmcnt(0)
    }
    if (tid < 16) dbuf[TT][tid] = 0.0f;       // mask row for t=127 write-side
    __syncthreads();   // A: dbuf + ybuf[0] visible

    if (crit) {
        const int jcol = 16*w + c;
        // c state init (masked by done[0])
#pragma unroll
        for (int i = 0; i < 4; ++i) {
            float d0 = dbuf[0][4*q + i];
            float cv = c0[(size_t)(b0 + 4*q + i)*HH + jcol];
            cst[i] = (d0 != 0.0f) ? 0.0f : cv;
        }
        // h0 (masked) -> hbuf[0]
        int mm = tid & 15, j4 = (tid >> 4) & 15;
        float dm = dbuf[0][mm];
        f32x4 hv = *(const f32x4*)(h0 + (size_t)(b0 + mm)*HH + 4*j4);
#pragma unroll
        for (int ii = 0; ii < 4; ++ii)
            hbuf[0][mm][4*j4 + ii] = (dm != 0.0f) ? (short)0 : f2bf(hv[ii]);
    } else {
        // gy[0] = bias + y0@Wih^T
        Frag yc0, yc1;
        yc0.s = *(const s16x8*)&ybuf[0][0][lane*8];
        yc1.s = *(const s16x8*)&ybuf[0][0][512 + lane*8];
#pragma unroll
        for (int a = 0; a < 4; ++a) {
            f32x4 gg = (f32x4){biasv[a], biasv[a], biasv[a], biasv[a]};
            gg = mfma16(yc0.b, wf[a][0].b, gg);
            gg = mfma16(yc1.b, wf[a][1].b, gg);
            *(f32x4*)&gybuf[0][hw][a][lane*4] = gg;
        }
    }
    __syncthreads();   // B: gybuf[0] + hbuf[0] ready

    for (int t = 0; t < TT; ++t) {
        if (crit) {
            const int jcol = 16*w + c;
            const int cur = t & 1;
            // ---- critical chain: h frags + gy -> 8 MFMA -> elementwise
            Frag hf0, hf1;
            hf0.s = *(const s16x8*)&hbuf[cur][c][8*q];
            hf1.s = *(const s16x8*)&hbuf[cur][c][32 + 8*q];
            f32x4 acc[4];
#pragma unroll
            for (int a = 0; a < 4; ++a) acc[a] = *(const f32x4*)&gybuf[cur][w][a][lane*4];
#pragma unroll
            for (int a = 0; a < 4; ++a) {
                acc[a] = mfma16(hf0.b, wf[a][0].b, acc[a]);
                acc[a] = mfma16(hf1.b, wf[a][1].b, acc[a]);
            }
            const f32x4 dn = *(const f32x4*)&dbuf[t+1][4*q];   // mask for NEXT step
#pragma unroll
            for (int i = 0; i < 4; ++i) {
                float gi = acc[0][i], gf = acc[1][i], gg = acc[2][i], go = acc[3][i];
                float cn = sigm(gf)*cst[i] + sigm(gi)*tanh_fast(gg);
                float h  = sigm(go)*tanh_fast(cn);
                short zb = f2bf(h);
                zbuf[cur][4*q + i][jcol] = zb;                  // unmasked (output)
                const bool d = (dn[i] != 0.0f);
                cst[i] = d ? 0.0f : cn;                         // write-side mask
                hbuf[cur ^ 1][4*q + i][jcol] = d ? (short)0 : zb;
            }
        } else {
            // ---- helpers: staging / flush / head / gy[t+1]
            if ((t & 7) == 0 && t < 120) {        // stage y chunk (t/8)+1
                const int k = (t >> 3) + 1;
#pragma unroll
                for (int i = 0; i < 4; ++i) {
                    int idx = hw*4 + i, ss = idx >> 1, half = idx & 1;
                    const short* gp = y_sw + ((size_t)(8*k + ss)*128 + blk)*1024 + half*512 + lane*8;
                    GLDS(gp, &ybuf[k & 1][ss][half*512]);
                }
            }
            if ((t & 7) == 1 && t > 8 && w < 6) { // flush chunk (t/8)-1 outputs
                const int cc = (t >> 3) - 1;
                const int idx = (w - 4)*64 + lane;   // 0..127
                const int s = idx >> 4, r = idx & 15;
                const size_t row = (size_t)(8*cc + s)*BB + b0 + r;
                const float* ob = &obuf[cc & 1][s][r][0];
                float* lp = out_logits + row*AA;
#pragma unroll
                for (int n = 0; n < 15; ++n) lp[n] = ob[n];
                out_vf[row] = ob[15];
            }
            if (t >= 1 && w == 4 + ((t-1) & 3)) { // head for z[t-1]
                const int tp = t - 1;
                Frag zf0, zf1;
                zf0.s = *(const s16x8*)&zbuf[tp & 1][c][8*q];
                zf1.s = *(const s16x8*)&zbuf[tp & 1][c][32 + 8*q];
                f32x4 ha = (f32x4){hbv, hbv, hbv, hbv};
                ha = mfma16(zf0.b, hwf[0].b, ha);
                ha = mfma16(zf1.b, hwf[1].b, ha);
#pragma unroll
                for (int i = 0; i < 4; ++i)
                    obuf[(tp >> 3) & 1][tp & 7][4*q + i][c] = ha[i];
            }
            if (t < TT-1) {                        // gy[t+1]
                const int tn = t + 1;
                const int ch = (tn >> 3) & 1, sl = tn & 7;
                Frag yc0, yc1;
                yc0.s = *(const s16x8*)&ybuf[ch][sl][lane*8];
                yc1.s = *(const s16x8*)&ybuf[ch][sl][512 + lane*8];
#pragma unroll
                for (int a = 0; a < 4; ++a) {
                    f32x4 g = (f32x4){biasv[a], biasv[a], biasv[a], biasv[a]};
                    g = mfma16(yc0.b, wf[a][0].b, g);
                    g = mfma16(yc1.b, wf[a][1].b, g);
                    *(f32x4*)&gybuf[tn & 1][hw][a][lane*4] = g;
                }
            }
            if ((t & 7) == 6)                      // drain staging off crit path
                __builtin_amdgcn_s_waitcnt(0x0F70);
        }
        block_sync_lds();   // lgkmcnt-only barrier: vmem stays in flight
    }

    // ---------------- epilogue ----------------
    if (!crit && w == 7) {                         // head for z[127]
        Frag zf0, zf1;
        zf0.s = *(const s16x8*)&zbuf[1][c][8*q];
        zf1.s = *(const s16x8*)&zbuf[1][c][32 + 8*q];
        f32x4 ha = (f32x4){hbv, hbv, hbv, hbv};
        ha = mfma16(zf0.b, hwf[0].b, ha);
        ha = mfma16(zf1.b, hwf[1].b, ha);
#pragma unroll
        for (int i = 0; i < 4; ++i) obuf[1][7][4*q + i][c] = ha[i];
    }
    __syncthreads();
    if (!crit && w < 6) {                          // flush chunk 15
        const int idx = (w - 4)*64 + lane;
        const int s = idx >> 4, r = idx & 15;
        const size_t row = (size_t)(120 + s)*BB + b0 + r;
        const float* ob = &obuf[1][s][r][0];
        float* lp = out_logits + row*AA;
#pragma unroll
        for (int n = 0; n < 15; ++n) lp[n] = ob[n];
        out_vf[row] = ob[15];
    }
    if (crit) {
        const int jcol = 16*w + c;
        int mm = tid & 15, j4 = (tid >> 4) & 15;
        f32x4 hv;
#pragma unroll
        for (int ii = 0; ii < 4; ++ii) hv[ii] = bf2f(zbuf[1][mm][4*j4 + ii]);  // z127 = hT
        *(f32x4*)(hT_out + (size_t)(b0 + mm)*HH + 4*j4) = hv;
#pragma unroll
        for (int i = 0; i < 4; ++i) cT_out[(size_t)(b0 + 4*q + i)*HH + jcol] = cst[i];
    }
}

// ============================ launch ============================
extern "C" void kernel_launch(void* const* d_in, const int* in_sizes, int n_in,
                              void* d_out, int out_size, void* d_ws, size_t ws_size,
                              hipStream_t stream) {
    const float* x    = (const float*)d_in[0];
    const float* done = (const float*)d_in[1];
    const float* h0   = (const float*)d_in[2];
    const float* c0   = (const float*)d_in[3];
    const float* W1   = (const float*)d_in[4];
    const float* b1   = (const float*)d_in[5];
    const float* W2   = (const float*)d_in[6];
    const float* b2   = (const float*)d_in[7];
    const float* Wih  = (const float*)d_in[8];
    const float* bih  = (const float*)d_in[9];
    const float* Whh  = (const float*)d_in[10];
    const float* bhh  = (const float*)d_in[11];
    const float* Wa   = (const float*)d_in[12];
    const float* ba   = (const float*)d_in[13];
    const float* Wc   = (const float*)d_in[14];
    const float* bc   = (const float*)d_in[15];
    float* out = (float*)d_out;

    short* y_sw = (short*)d_ws;     // 32 MiB swizzled encoder output

    enc_kernel<<<1024, 256, 0, stream>>>(x, W1, b1, W2, b2, y_sw);
    scan_kernel<<<128, 512, 0, stream>>>(y_sw, done, h0, c0, Wih, bih, Whh, bhh,
                                         Wa, ba, Wc, bc,
                                         out + LOGITS_OFF, out + VF_OFF,
                                         out + HT_OFF, out + CT_OFF);
}

// Round 3
// 310.194 us; speedup vs baseline: 1.1157x; 1.0381x over previous
//
#include <hip/hip_runtime.h>
#include <hip/hip_bf16.h>
#include <stdint.h>

// ---------- types ----------
typedef __bf16  bf16x8 __attribute__((ext_vector_type(8)));
typedef short   s16x8  __attribute__((ext_vector_type(8)));
typedef int     i32x4  __attribute__((ext_vector_type(4)));
typedef float   f32x4  __attribute__((ext_vector_type(4)));

union Frag { s16x8 s; bf16x8 b; i32x4 i; };

static __device__ __forceinline__ short f2bf(float f) {
    union { float f; unsigned u; } v; v.f = f;
    unsigned r = (v.u + 0x7FFFu + ((v.u >> 16) & 1u)) >> 16;   // RNE
    return (short)r;
}
static __device__ __forceinline__ float bf2f(short s) {
    union { unsigned u; float f; } v; v.u = ((unsigned)(unsigned short)s) << 16;
    return v.f;
}
static __device__ __forceinline__ float fast_rcp(float x) { return __builtin_amdgcn_rcpf(x); }
static __device__ __forceinline__ float sigm(float x) { return fast_rcp(1.0f + __expf(-x)); }
static __device__ __forceinline__ float tanh_fast(float x) {
    float e = __expf(-2.0f * x);
    return (1.0f - e) * fast_rcp(1.0f + e);
}
static __device__ __forceinline__ f32x4 mfma16(bf16x8 a, bf16x8 b, f32x4 c) {
    return __builtin_amdgcn_mfma_f32_16x16x32_bf16(a, b, c, 0, 0, 0);
}

// Barrier that does NOT drain vmcnt (LDS-visibility only).
static __device__ __forceinline__ void block_sync_lds() {
    asm volatile("s_waitcnt lgkmcnt(0)\n\ts_barrier" ::: "memory");
}

#define GLDS(gp, lp) __builtin_amdgcn_global_load_lds( \
    (const __attribute__((address_space(1))) void*)(gp), \
    (__attribute__((address_space(3))) void*)(lp), 16, 0, 0)

// Constants
#define TT 128
#define BB 2048
#define HH 64
#define FF 128
#define AA 15
#define CH 8                  // y staging chunk (steps), double-buffered
#define LOGITS_OFF 0
#define VF_OFF   3932160
#define HT_OFF   4194304
#define CT_OFF   4325376

// y_sw layout (8-row records): record (t, g8) with g8 = batch-octet index 0..255,
// 512 bf16 = [lane(64) = kf*32 + c8*4 + q][8]  (A-frag order for rows c8 = 0..7)

// ============================ encoder ============================
__global__ __launch_bounds__(256) void enc_kernel(
    const float* __restrict__ x, const float* __restrict__ W1, const float* __restrict__ b1,
    const float* __restrict__ W2, const float* __restrict__ b2, short* __restrict__ y_sw)
{
    __shared__ short w1t[64][136];
    __shared__ short w2t[64][72];
    __shared__ short c1buf[4][16][72];
    __shared__ short ybuf[4][16][72];

    const int tid  = threadIdx.x;
    const int lane = tid & 63;
    const int w    = tid >> 6;
    const int c    = lane & 15;
    const int q    = lane >> 4;

    for (int i = tid; i < 128*64; i += 256) { int k = i >> 6, n = i & 63; w1t[n][k] = f2bf(W1[i]); }
    for (int i = tid; i < 64*64;  i += 256) { int k = i >> 6, n = i & 63; w2t[n][k] = f2bf(W2[i]); }

    float b1v[4], b2v[4];
#pragma unroll
    for (int ct = 0; ct < 4; ++ct) { b1v[ct] = b1[16*ct + c]; b2v[ct] = b2[16*ct + c]; }
    __syncthreads();

    for (int it = 0; it < 4; ++it) {
        const int wt = it*4096 + blockIdx.x*4 + w;
        const int r0 = wt * 16;
        Frag af[4];
#pragma unroll
        for (int kf = 0; kf < 4; ++kf) {
            const float* xp = x + (size_t)(r0 + c)*FF + 32*kf + 8*q;
            f32x4 x0 = *(const f32x4*)xp;
            f32x4 x1 = *(const f32x4*)(xp + 4);
#pragma unroll
            for (int jj = 0; jj < 4; ++jj) { af[kf].s[jj] = f2bf(x0[jj]); af[kf].s[4+jj] = f2bf(x1[jj]); }
        }
        f32x4 acc[4];
#pragma unroll
        for (int ct = 0; ct < 4; ++ct) acc[ct] = (f32x4){b1v[ct], b1v[ct], b1v[ct], b1v[ct]};
#pragma unroll
        for (int kf = 0; kf < 4; ++kf)
#pragma unroll
            for (int ct = 0; ct < 4; ++ct) {
                Frag bf; bf.s = *(const s16x8*)&w1t[16*ct + c][32*kf + 8*q];
                acc[ct] = mfma16(af[kf].b, bf.b, acc[ct]);
            }
#pragma unroll
        for (int ct = 0; ct < 4; ++ct)
#pragma unroll
            for (int i = 0; i < 4; ++i)
                c1buf[w][4*q + i][16*ct + c] = f2bf(tanh_fast(acc[ct][i]));
        Frag a2[2];
#pragma unroll
        for (int kf = 0; kf < 2; ++kf) a2[kf].s = *(const s16x8*)&c1buf[w][c][32*kf + 8*q];
        f32x4 acc2[4];
#pragma unroll
        for (int ct = 0; ct < 4; ++ct) acc2[ct] = (f32x4){b2v[ct], b2v[ct], b2v[ct], b2v[ct]};
#pragma unroll
        for (int kf = 0; kf < 2; ++kf)
#pragma unroll
            for (int ct = 0; ct < 4; ++ct) {
                Frag bf; bf.s = *(const s16x8*)&w2t[16*ct + c][32*kf + 8*q];
                acc2[ct] = mfma16(a2[kf].b, bf.b, acc2[ct]);
            }
#pragma unroll
        for (int ct = 0; ct < 4; ++ct)
#pragma unroll
            for (int i = 0; i < 4; ++i)
                ybuf[w][4*q + i][16*ct + c] = f2bf(tanh_fast(acc2[ct][i]));
        // ---- store as two 8-row records (coalesced: lane*16B within each record)
        {
            const int kf2 = lane >> 5;          // 0..1
            const int c8  = (lane >> 2) & 7;    // 0..7
            const int qq  = lane & 3;           // 0..3
#pragma unroll
            for (int g = 0; g < 2; ++g) {
                s16x8 yv = *(const s16x8*)&ybuf[w][c8 + 8*g][32*kf2 + 8*qq];
                *(s16x8*)(y_sw + ((size_t)(wt >> 7)*256 + (size_t)(wt & 127)*2 + g)*512 + lane*8) = yv;
            }
        }
    }
}

// ============================ LSTM scan (256 blocks x 8 batch rows) ============================
// 256 blocks x 512 thr (all 256 CUs). Waves 0-3: crit (h@Whh MFMA + elementwise).
// MFMA M=16 tile carries 8 valid batch rows (lanes c>=8 read duplicated rows -> finite,
// discarded). After the gate MFMA, ds_bpermute(lane^32) redistributes acc rows {2,3}/{6,7}
// to the q>=2 lanes so ALL 64 lanes run the LSTM nonlinearity for 2 real cells each
// (halves crit-wave VALU issue vs 4 cells/lane on 128 blocks).
// Waves 4-7: helpers (gy[t+1], y staging via global_load_lds, heads, flush).
__global__ __launch_bounds__(512, 1) void scan_kernel(
    const short* __restrict__ y_sw, const float* __restrict__ done,
    const float* __restrict__ h0, const float* __restrict__ c0,
    const float* __restrict__ Wih, const float* __restrict__ bih,
    const float* __restrict__ Whh, const float* __restrict__ bhh,
    const float* __restrict__ Wa, const float* __restrict__ ba,
    const float* __restrict__ Wc, const float* __restrict__ bc,
    float* __restrict__ out_logits, float* __restrict__ out_vf,
    float* __restrict__ hT_out, float* __restrict__ cT_out)
{
    __shared__ short ybuf[2][CH][512];      // 16 KB  staged y (A-frag order), dbl-buf
    __shared__ float gybuf[2][4][4][128];   // 16 KB  gy = bias + y@Wih^T (valid lanes 0-31)
    __shared__ float obuf[2][CH][8][16];    // 8 KB   head outputs, dbl-buf by chunk
    __shared__ short zbuf[2][8][72];        // 2.3 KB unmasked h (for heads/hT)
    __shared__ short hbuf[2][8][72];        // 2.3 KB masked h (scan state)
    __shared__ float dbuf[TT+1][8];         // 4.1 KB done, +zero row 128

    const int tid  = threadIdx.x;
    const int lane = tid & 63;
    const int w    = tid >> 6;
    const int c    = lane & 15;
    const int q    = lane >> 4;
    const int blk  = blockIdx.x;
    const int b0   = blk * 8;
    const bool crit = (w < 4);
    const int hw   = w - 4;
    // row pair owned by this crit lane after redistribution:
    // q=0 -> {0,1}, q=1 -> {4,5}, q=2 -> {2,3}, q=3 -> {6,7}
    const int r0   = 4*(q & 1) + 2*(q >> 1);

    // ---------------- per-role register state ----------------
    Frag  wf[4][2];      // crit: Whh B-frags        helper: Wih B-frags
    float biasv[4];      // helper only
    Frag  hwf[2];        // helper: head B-frags
    float hbv = 0.f;     // helper: head bias
    float cst0 = 0.f, cst1 = 0.f;   // crit: c state (2 cells)

    if (crit) {
        const int jcol = 16*w + c;
#pragma unroll
        for (int a = 0; a < 4; ++a) {
            const int col = 64*a + jcol;
#pragma unroll
            for (int kf = 0; kf < 2; ++kf) {
                const float* wp = Whh + (size_t)col*HH + 32*kf + 8*q;
                f32x4 w0 = *(const f32x4*)wp;
                f32x4 w1 = *(const f32x4*)(wp + 4);
#pragma unroll
                for (int jj = 0; jj < 4; ++jj) { wf[a][kf].s[jj] = f2bf(w0[jj]); wf[a][kf].s[4+jj] = f2bf(w1[jj]); }
            }
        }
    } else {
        const int jcolh = 16*hw + c;
#pragma unroll
        for (int a = 0; a < 4; ++a) {
            const int col = 64*a + jcolh;
            biasv[a] = bih[col] + bhh[col];
#pragma unroll
            for (int kf = 0; kf < 2; ++kf) {
                const float* wp = Wih + (size_t)col*HH + 32*kf + 8*q;
                f32x4 w0 = *(const f32x4*)wp;
                f32x4 w1 = *(const f32x4*)(wp + 4);
#pragma unroll
                for (int jj = 0; jj < 4; ++jj) { wf[a][kf].s[jj] = f2bf(w0[jj]); wf[a][kf].s[4+jj] = f2bf(w1[jj]); }
            }
        }
#pragma unroll
        for (int kf = 0; kf < 2; ++kf)
#pragma unroll
            for (int jj = 0; jj < 8; ++jj) {
                int k = 32*kf + 8*q + jj;
                hwf[kf].s[jj] = f2bf((c < 15) ? Wa[k*AA + c] : Wc[k]);
            }
        hbv = (c < 15) ? ba[c] : bc[0];
        // ---- stage done (32 steps per wave, 8 floats per step) + y chunk 0
        {
            const int t0 = hw * 32;
            const float* gp = done + (size_t)(t0 + (lane >> 1))*BB + b0 + 4*(lane & 1);
            GLDS(gp, &dbuf[t0][0]);
        }
#pragma unroll
        for (int i = 0; i < 2; ++i) {
            const int ss = hw*2 + i;    // t within chunk 0
            const short* gp = y_sw + ((size_t)ss*256 + blk)*512 + lane*8;
            GLDS(gp, &ybuf[0][ss][0]);
        }
        __builtin_amdgcn_s_waitcnt(0x0F70);   // vmcnt(0)
    }
    if (tid < 8) dbuf[TT][tid] = 0.0f;        // mask row for t=127 write-side
    __syncthreads();   // A: dbuf + ybuf[0] visible

    if (crit) {
        const int jcol = 16*w + c;
        // c state init (masked by done[0]) for this lane's 2 rows
        {
            float d0 = dbuf[0][r0 + 0];
            float d1 = dbuf[0][r0 + 1];
            float cv0 = c0[(size_t)(b0 + r0 + 0)*HH + jcol];
            float cv1 = c0[(size_t)(b0 + r0 + 1)*HH + jcol];
            cst0 = (d0 != 0.0f) ? 0.0f : cv0;
            cst1 = (d1 != 0.0f) ? 0.0f : cv1;
        }
        // h0 (masked) -> hbuf[0]  (8 rows x 64 cols, 4 cols/thread)
        if (tid < 128) {
            int mm = tid & 7, j4 = (tid >> 3) & 15;
            float dm = dbuf[0][mm];
            f32x4 hv = *(const f32x4*)(h0 + (size_t)(b0 + mm)*HH + 4*j4);
#pragma unroll
            for (int ii = 0; ii < 4; ++ii)
                hbuf[0][mm][4*j4 + ii] = (dm != 0.0f) ? (short)0 : f2bf(hv[ii]);
        }
    } else {
        // gy[0] = bias + y0@Wih^T
        Frag yc0, yc1;
        yc0.s = *(const s16x8*)&ybuf[0][0][((c & 7)*4 + q)*8];
        yc1.s = *(const s16x8*)&ybuf[0][0][(32 + (c & 7)*4 + q)*8];
#pragma unroll
        for (int a = 0; a < 4; ++a) {
            f32x4 gg = (f32x4){biasv[a], biasv[a], biasv[a], biasv[a]};
            gg = mfma16(yc0.b, wf[a][0].b, gg);
            gg = mfma16(yc1.b, wf[a][1].b, gg);
            if (lane < 32) *(f32x4*)&gybuf[0][hw][a][lane*4] = gg;
        }
    }
    __syncthreads();   // B: gybuf[0] + hbuf[0] ready

    for (int t = 0; t < TT; ++t) {
        if (crit) {
            const int jcol = 16*w + c;
            const int cur = t & 1;
            // ---- critical chain: h frags + gy -> 8 MFMA -> redistribute -> elementwise
            Frag hf0, hf1;
            hf0.s = *(const s16x8*)&hbuf[cur][c & 7][8*q];
            hf1.s = *(const s16x8*)&hbuf[cur][c & 7][32 + 8*q];
            f32x4 acc[4];
#pragma unroll
            for (int a = 0; a < 4; ++a) acc[a] = *(const f32x4*)&gybuf[cur][w][a][(lane & 31)*4];
#pragma unroll
            for (int a = 0; a < 4; ++a) {
                acc[a] = mfma16(hf0.b, wf[a][0].b, acc[a]);
                acc[a] = mfma16(hf1.b, wf[a][1].b, acc[a]);
            }
            // redistribute rows {2,3}/{6,7} to q>=2 lanes (partner = lane^32)
            const int pidx = (lane ^ 32) << 2;
            float g0[4], g1[4];
            const bool hiq = (q >= 2);
#pragma unroll
            for (int a = 0; a < 4; ++a) {
                float s0 = __int_as_float(__builtin_amdgcn_ds_bpermute(pidx, __float_as_int(acc[a][2])));
                float s1 = __int_as_float(__builtin_amdgcn_ds_bpermute(pidx, __float_as_int(acc[a][3])));
                g0[a] = hiq ? s0 : acc[a][0];
                g1[a] = hiq ? s1 : acc[a][1];
            }
            const float dn0 = dbuf[t+1][r0 + 0];   // mask for NEXT step
            const float dn1 = dbuf[t+1][r0 + 1];
            // ---- elementwise, 2 cells/lane (fused-rcp: 5 exp + 3 rcp per cell)
#define ELEM(GV, CSTV, RI, DN) {                                        \
            float ei = __expf(-GV[0]), ef = __expf(-GV[1]);             \
            float eg = __expf(-2.0f*GV[2]), eo = __expf(-GV[3]);        \
            float term = (1.0f - eg) * fast_rcp((1.0f + ei)*(1.0f + eg)); \
            float cn = fast_rcp(1.0f + ef)*CSTV + term;                 \
            float ec = __expf(-2.0f*cn);                                \
            float hv = (1.0f - ec) * fast_rcp((1.0f + eo)*(1.0f + ec)); \
            short zb = f2bf(hv);                                        \
            zbuf[cur][RI][jcol] = zb;                                   \
            const bool d = ((DN) != 0.0f);                              \
            CSTV = d ? 0.0f : cn;                                       \
            hbuf[cur ^ 1][RI][jcol] = d ? (short)0 : zb; }
            ELEM(g0, cst0, r0 + 0, dn0)
            ELEM(g1, cst1, r0 + 1, dn1)
#undef ELEM
        } else {
            // ---- helpers: staging / flush / head / gy[t+1]
            if ((t & 7) == 0 && t < 120) {        // stage y chunk (t/8)+1
                const int k = (t >> 3) + 1;
#pragma unroll
                for (int i = 0; i < 2; ++i) {
                    const int ss = hw*2 + i;
                    const short* gp = y_sw + ((size_t)(8*k + ss)*256 + blk)*512 + lane*8;
                    GLDS(gp, &ybuf[k & 1][ss][0]);
                }
            }
            if ((t & 7) == 1 && t > 8 && w == 4) { // flush chunk (t/8)-1 outputs
                const int cc = (t >> 3) - 1;
                const int s = lane >> 3, r = lane & 7;
                const size_t row = (size_t)(8*cc + s)*BB + b0 + r;
                const float* ob = &obuf[cc & 1][s][r][0];
                float* lp = out_logits + row*AA;
#pragma unroll
                for (int n = 0; n < 15; ++n) lp[n] = ob[n];
                out_vf[row] = ob[15];
            }
            if (t >= 1 && w == 4 + ((t + 2) & 3)) { // head for z[t-1] (offset avoids flush wave)
                const int tp = t - 1;
                Frag zf0, zf1;
                zf0.s = *(const s16x8*)&zbuf[tp & 1][c & 7][8*q];
                zf1.s = *(const s16x8*)&zbuf[tp & 1][c & 7][32 + 8*q];
                f32x4 ha = (f32x4){hbv, hbv, hbv, hbv};
                ha = mfma16(zf0.b, hwf[0].b, ha);
                ha = mfma16(zf1.b, hwf[1].b, ha);
                if (q < 2) {
#pragma unroll
                    for (int i = 0; i < 4; ++i)
                        obuf[(tp >> 3) & 1][tp & 7][4*q + i][c] = ha[i];
                }
            }
            if (t < TT-1) {                        // gy[t+1]
                const int tn = t + 1;
                const int ch = (tn >> 3) & 1, sl = tn & 7;
                Frag yc0, yc1;
                yc0.s = *(const s16x8*)&ybuf[ch][sl][((c & 7)*4 + q)*8];
                yc1.s = *(const s16x8*)&ybuf[ch][sl][(32 + (c & 7)*4 + q)*8];
#pragma unroll
                for (int a = 0; a < 4; ++a) {
                    f32x4 g = (f32x4){biasv[a], biasv[a], biasv[a], biasv[a]};
                    g = mfma16(yc0.b, wf[a][0].b, g);
                    g = mfma16(yc1.b, wf[a][1].b, g);
                    if (lane < 32) *(f32x4*)&gybuf[tn & 1][hw][a][lane*4] = g;
                }
            }
            if ((t & 7) == 6)                      // drain staging off crit path
                __builtin_amdgcn_s_waitcnt(0x0F70);
        }
        block_sync_lds();   // lgkmcnt-only barrier: vmem stays in flight
    }

    // ---------------- epilogue ----------------
    if (!crit && w == 7) {                         // head for z[127]
        Frag zf0, zf1;
        zf0.s = *(const s16x8*)&zbuf[1][c & 7][8*q];
        zf1.s = *(const s16x8*)&zbuf[1][c & 7][32 + 8*q];
        f32x4 ha = (f32x4){hbv, hbv, hbv, hbv};
        ha = mfma16(zf0.b, hwf[0].b, ha);
        ha = mfma16(zf1.b, hwf[1].b, ha);
        if (q < 2) {
#pragma unroll
            for (int i = 0; i < 4; ++i) obuf[1][7][4*q + i][c] = ha[i];
        }
    }
    __syncthreads();
    if (!crit && w == 4) {                         // flush chunk 15
        const int s = lane >> 3, r = lane & 7;
        const size_t row = (size_t)(120 + s)*BB + b0 + r;
        const float* ob = &obuf[1][s][r][0];
        float* lp = out_logits + row*AA;
#pragma unroll
        for (int n = 0; n < 15; ++n) lp[n] = ob[n];
        out_vf[row] = ob[15];
    }
    if (tid < 128) {                               // hT = z127
        int mm = tid & 7, j4 = (tid >> 3) & 15;
        f32x4 hv;
#pragma unroll
        for (int ii = 0; ii < 4; ++ii) hv[ii] = bf2f(zbuf[1][mm][4*j4 + ii]);
        *(f32x4*)(hT_out + (size_t)(b0 + mm)*HH + 4*j4) = hv;
    }
    if (crit) {
        const int jcol = 16*w + c;
        cT_out[(size_t)(b0 + r0 + 0)*HH + jcol] = cst0;
        cT_out[(size_t)(b0 + r0 + 1)*HH + jcol] = cst1;
    }
}

// ============================ launch ============================
extern "C" void kernel_launch(void* const* d_in, const int* in_sizes, int n_in,
                              void* d_out, int out_size, void* d_ws, size_t ws_size,
                              hipStream_t stream) {
    const float* x    = (const float*)d_in[0];
    const float* done = (const float*)d_in[1];
    const float* h0   = (const float*)d_in[2];
    const float* c0   = (const float*)d_in[3];
    const float* W1   = (const float*)d_in[4];
    const float* b1   = (const float*)d_in[5];
    const float* W2   = (const float*)d_in[6];
    const float* b2   = (const float*)d_in[7];
    const float* Wih  = (const float*)d_in[8];
    const float* bih  = (const float*)d_in[9];
    const float* Whh  = (const float*)d_in[10];
    const float* bhh  = (const float*)d_in[11];
    const float* Wa   = (const float*)d_in[12];
    const float* ba   = (const float*)d_in[13];
    const float* Wc   = (const float*)d_in[14];
    const float* bc   = (const float*)d_in[15];
    float* out = (float*)d_out;

    short* y_sw = (short*)d_ws;     // 32 MiB swizzled encoder output (8-row records)

    enc_kernel<<<1024, 256, 0, stream>>>(x, W1, b1, W2, b2, y_sw);
    scan_kernel<<<256, 512, 0, stream>>>(y_sw, done, h0, c0, Wih, bih, Whh, bhh,
                                         Wa, ba, Wc, bc,
                                         out + LOGITS_OFF, out + VF_OFF,
                                         out + HT_OFF, out + CT_OFF);
}

// Round 5
// 295.029 us; speedup vs baseline: 1.1730x; 1.0514x over previous
//
#include <hip/hip_runtime.h>
#include <hip/hip_bf16.h>
#include <stdint.h>

// ---------- types ----------
typedef __bf16  bf16x8 __attribute__((ext_vector_type(8)));
typedef short   s16x8  __attribute__((ext_vector_type(8)));
typedef int     i32x4  __attribute__((ext_vector_type(4)));
typedef float   f32x4  __attribute__((ext_vector_type(4)));

union Frag { s16x8 s; bf16x8 b; i32x4 i; };

static __device__ __forceinline__ short f2bf(float f) {
    union { float f; unsigned u; } v; v.f = f;
    unsigned r = (v.u + 0x7FFFu + ((v.u >> 16) & 1u)) >> 16;   // RNE
    return (short)r;
}
static __device__ __forceinline__ float bf2f(short s) {
    union { unsigned u; float f; } v; v.u = ((unsigned)(unsigned short)s) << 16;
    return v.f;
}
static __device__ __forceinline__ float fast_rcp(float x) { return __builtin_amdgcn_rcpf(x); }
static __device__ __forceinline__ float sigm(float x) { return fast_rcp(1.0f + __expf(-x)); }
static __device__ __forceinline__ float tanh_fast(float x) {
    float e = __expf(-2.0f * x);
    return (1.0f - e) * fast_rcp(1.0f + e);
}
static __device__ __forceinline__ f32x4 mfma16(bf16x8 a, bf16x8 b, f32x4 c) {
    return __builtin_amdgcn_mfma_f32_16x16x32_bf16(a, b, c, 0, 0, 0);
}

// Barrier that does NOT drain vmcnt (LDS-visibility only).
static __device__ __forceinline__ void block_sync_lds() {
    asm volatile("s_waitcnt lgkmcnt(0)\n\ts_barrier" ::: "memory");
}

#define GLDS(gp, lp) __builtin_amdgcn_global_load_lds( \
    (const __attribute__((address_space(1))) void*)(gp), \
    (__attribute__((address_space(3))) void*)(lp), 16, 0, 0)

// Constants
#define TT 128
#define BB 2048
#define HH 64
#define FF 128
#define AA 15
#define CH 8                  // y staging chunk (steps), double-buffered
#define LOGITS_OFF 0
#define VF_OFF   3932160
#define HT_OFF   4194304
#define CT_OFF   4325376

// y_sw layout (8-row records): record (t, g8) with g8 = batch-octet index 0..255,
// 512 bf16 = [lane(64) = kf*32 + c8*4 + q][8]  (A-frag order for rows c8 = 0..7)

// ============================ encoder ============================
__global__ __launch_bounds__(256) void enc_kernel(
    const float* __restrict__ x, const float* __restrict__ W1, const float* __restrict__ b1,
    const float* __restrict__ W2, const float* __restrict__ b2, short* __restrict__ y_sw)
{
    __shared__ short w1t[64][136];
    __shared__ short w2t[64][72];
    __shared__ short c1buf[4][16][72];
    __shared__ short ybuf[4][16][72];

    const int tid  = threadIdx.x;
    const int lane = tid & 63;
    const int w    = tid >> 6;
    const int c    = lane & 15;
    const int q    = lane >> 4;

    for (int i = tid; i < 128*64; i += 256) { int k = i >> 6, n = i & 63; w1t[n][k] = f2bf(W1[i]); }
    for (int i = tid; i < 64*64;  i += 256) { int k = i >> 6, n = i & 63; w2t[n][k] = f2bf(W2[i]); }

    float b1v[4], b2v[4];
#pragma unroll
    for (int ct = 0; ct < 4; ++ct) { b1v[ct] = b1[16*ct + c]; b2v[ct] = b2[16*ct + c]; }
    __syncthreads();

    for (int it = 0; it < 4; ++it) {
        const int wt = it*4096 + blockIdx.x*4 + w;
        const int r0 = wt * 16;
        Frag af[4];
#pragma unroll
        for (int kf = 0; kf < 4; ++kf) {
            const float* xp = x + (size_t)(r0 + c)*FF + 32*kf + 8*q;
            f32x4 x0 = *(const f32x4*)xp;
            f32x4 x1 = *(const f32x4*)(xp + 4);
#pragma unroll
            for (int jj = 0; jj < 4; ++jj) { af[kf].s[jj] = f2bf(x0[jj]); af[kf].s[4+jj] = f2bf(x1[jj]); }
        }
        f32x4 acc[4];
#pragma unroll
        for (int ct = 0; ct < 4; ++ct) acc[ct] = (f32x4){b1v[ct], b1v[ct], b1v[ct], b1v[ct]};
#pragma unroll
        for (int kf = 0; kf < 4; ++kf)
#pragma unroll
            for (int ct = 0; ct < 4; ++ct) {
                Frag bf; bf.s = *(const s16x8*)&w1t[16*ct + c][32*kf + 8*q];
                acc[ct] = mfma16(af[kf].b, bf.b, acc[ct]);
            }
#pragma unroll
        for (int ct = 0; ct < 4; ++ct)
#pragma unroll
            for (int i = 0; i < 4; ++i)
                c1buf[w][4*q + i][16*ct + c] = f2bf(tanh_fast(acc[ct][i]));
        Frag a2[2];
#pragma unroll
        for (int kf = 0; kf < 2; ++kf) a2[kf].s = *(const s16x8*)&c1buf[w][c][32*kf + 8*q];
        f32x4 acc2[4];
#pragma unroll
        for (int ct = 0; ct < 4; ++ct) acc2[ct] = (f32x4){b2v[ct], b2v[ct], b2v[ct], b2v[ct]};
#pragma unroll
        for (int kf = 0; kf < 2; ++kf)
#pragma unroll
            for (int ct = 0; ct < 4; ++ct) {
                Frag bf; bf.s = *(const s16x8*)&w2t[16*ct + c][32*kf + 8*q];
                acc2[ct] = mfma16(a2[kf].b, bf.b, acc2[ct]);
            }
#pragma unroll
        for (int ct = 0; ct < 4; ++ct)
#pragma unroll
            for (int i = 0; i < 4; ++i)
                ybuf[w][4*q + i][16*ct + c] = f2bf(tanh_fast(acc2[ct][i]));
        // ---- store as two 8-row records (coalesced: lane*16B within each record)
        {
            const int kf2 = lane >> 5;          // 0..1
            const int c8  = (lane >> 2) & 7;    // 0..7
            const int qq  = lane & 3;           // 0..3
#pragma unroll
            for (int g = 0; g < 2; ++g) {
                s16x8 yv = *(const s16x8*)&ybuf[w][c8 + 8*g][32*kf2 + 8*qq];
                *(s16x8*)(y_sw + ((size_t)(wt >> 7)*256 + (size_t)(wt & 127)*2 + g)*512 + lane*8) = yv;
            }
        }
    }
}

// ============================ LSTM scan (256 blocks x 8 batch rows) ============================
// 256 blocks x 512 thr. Waves 0-3: crit — per step: h-frags -> 8 h-MFMAs accumulate
// onto register gy -> row self-select (MFMA rows 8-15 are bit-exact duplicates of
// rows 0-7 because the A-frag reads hbuf[c & 7]; a q>=2 lane's own acc[2],acc[3]
// ARE its rows r0,r0+1 — no cross-lane op needed) -> 2-cell elementwise -> write z/h
// -> register gy[t+1] = bias + y@Wih (hides under ELEM's VALU chain). No gybuf.
// Waves 4-7: helpers — y staging (global_load_lds), heads for z[t-1], output flush,
// vmcnt drain once per 8 steps. In-loop barrier is lgkmcnt-only.
__global__ __launch_bounds__(512, 1) void scan_kernel(
    const short* __restrict__ y_sw, const float* __restrict__ done,
    const float* __restrict__ h0, const float* __restrict__ c0,
    const float* __restrict__ Wih, const float* __restrict__ bih,
    const float* __restrict__ Whh, const float* __restrict__ bhh,
    const float* __restrict__ Wa, const float* __restrict__ ba,
    const float* __restrict__ Wc, const float* __restrict__ bc,
    float* __restrict__ out_logits, float* __restrict__ out_vf,
    float* __restrict__ hT_out, float* __restrict__ cT_out)
{
    __shared__ short ybuf[2][CH][512];      // 16 KB  staged y (A-frag order), dbl-buf
    __shared__ float obuf[2][CH][8][16];    // 8 KB   head outputs, dbl-buf by chunk
    __shared__ short zbuf[2][8][72];        // 2.3 KB unmasked h (for heads/hT)
    __shared__ short hbuf[2][8][72];        // 2.3 KB masked h (scan state)
    __shared__ float dbuf[TT+1][8];         // 4.1 KB done, +zero row 128

    const int tid  = threadIdx.x;
    const int lane = tid & 63;
    const int w    = tid >> 6;
    const int c    = lane & 15;
    const int q    = lane >> 4;
    const int blk  = blockIdx.x;
    const int b0   = blk * 8;
    const bool crit = (w < 4);
    const int hw   = w - 4;
    // row pair owned by this crit lane:
    // q=0 -> {0,1}, q=1 -> {4,5}, q=2 -> {2,3}, q=3 -> {6,7}
    const int r0   = 4*(q & 1) + 2*(q >> 1);

    // ---------------- per-role register state ----------------
    Frag  wf[4][2];      // crit: Whh B-frags
    Frag  wfi[4][2];     // crit: Wih B-frags
    float biasv[4];      // crit: bih+bhh
    Frag  hwf[2];        // helper: head B-frags
    float hbv = 0.f;     // helper: head bias
    float cst0 = 0.f, cst1 = 0.f;   // crit: c state (2 cells)
    f32x4 gyr[4];        // crit: running gate pre-activation (bias + y@Wih)

    if (crit) {
        const int jcol = 16*w + c;
#pragma unroll
        for (int a = 0; a < 4; ++a) {
            const int col = 64*a + jcol;
            biasv[a] = bih[col] + bhh[col];
#pragma unroll
            for (int kf = 0; kf < 2; ++kf) {
                const float* wp = Whh + (size_t)col*HH + 32*kf + 8*q;
                f32x4 w0 = *(const f32x4*)wp;
                f32x4 w1 = *(const f32x4*)(wp + 4);
#pragma unroll
                for (int jj = 0; jj < 4; ++jj) { wf[a][kf].s[jj] = f2bf(w0[jj]); wf[a][kf].s[4+jj] = f2bf(w1[jj]); }
                const float* vp = Wih + (size_t)col*HH + 32*kf + 8*q;
                f32x4 v0 = *(const f32x4*)vp;
                f32x4 v1 = *(const f32x4*)(vp + 4);
#pragma unroll
                for (int jj = 0; jj < 4; ++jj) { wfi[a][kf].s[jj] = f2bf(v0[jj]); wfi[a][kf].s[4+jj] = f2bf(v1[jj]); }
            }
        }
    } else {
#pragma unroll
        for (int kf = 0; kf < 2; ++kf)
#pragma unroll
            for (int jj = 0; jj < 8; ++jj) {
                int k = 32*kf + 8*q + jj;
                hwf[kf].s[jj] = f2bf((c < 15) ? Wa[k*AA + c] : Wc[k]);
            }
        hbv = (c < 15) ? ba[c] : bc[0];
        // ---- stage done (32 steps per wave, 8 floats per step) + y chunk 0
        {
            const int t0 = hw * 32;
            const float* gp = done + (size_t)(t0 + (lane >> 1))*BB + b0 + 4*(lane & 1);
            GLDS(gp, &dbuf[t0][0]);
        }
#pragma unroll
        for (int i = 0; i < 2; ++i) {
            const int ss = hw*2 + i;    // t within chunk 0
            const short* gp = y_sw + ((size_t)ss*256 + blk)*512 + lane*8;
            GLDS(gp, &ybuf[0][ss][0]);
        }
        __builtin_amdgcn_s_waitcnt(0x0F70);   // vmcnt(0)
    }
    if (tid < 8) dbuf[TT][tid] = 0.0f;        // mask row for t=127 write-side
    __syncthreads();   // A: dbuf + ybuf[0] visible

    if (crit) {
        const int jcol = 16*w + c;
        // c state init (masked by done[0]) for this lane's 2 rows
        {
            float d0 = dbuf[0][r0 + 0];
            float d1 = dbuf[0][r0 + 1];
            float cv0 = c0[(size_t)(b0 + r0 + 0)*HH + jcol];
            float cv1 = c0[(size_t)(b0 + r0 + 1)*HH + jcol];
            cst0 = (d0 != 0.0f) ? 0.0f : cv0;
            cst1 = (d1 != 0.0f) ? 0.0f : cv1;
        }
        // h0 (masked) -> hbuf[0]  (8 rows x 64 cols, 4 cols/thread)
        if (tid < 128) {
            int mm = tid & 7, j4 = (tid >> 3) & 15;
            float dm = dbuf[0][mm];
            f32x4 hv = *(const f32x4*)(h0 + (size_t)(b0 + mm)*HH + 4*j4);
#pragma unroll
            for (int ii = 0; ii < 4; ++ii)
                hbuf[0][mm][4*j4 + ii] = (dm != 0.0f) ? (short)0 : f2bf(hv[ii]);
        }
        // gy[0] = bias + y0@Wih^T  (registers)
        {
            Frag yc0, yc1;
            yc0.s = *(const s16x8*)&ybuf[0][0][((c & 7)*4 + q)*8];
            yc1.s = *(const s16x8*)&ybuf[0][0][(32 + (c & 7)*4 + q)*8];
#pragma unroll
            for (int a = 0; a < 4; ++a) {
                f32x4 g = (f32x4){biasv[a], biasv[a], biasv[a], biasv[a]};
                g = mfma16(yc0.b, wfi[a][0].b, g);
                g = mfma16(yc1.b, wfi[a][1].b, g);
                gyr[a] = g;
            }
        }
    }
    __syncthreads();   // B: hbuf[0] ready

    for (int t = 0; t < TT; ++t) {
        if (crit) {
            const int jcol = 16*w + c;
            const int cur = t & 1;
            // ---- critical chain: h frags -> 8 MFMA onto register gy
            Frag hf0, hf1;
            hf0.s = *(const s16x8*)&hbuf[cur][c & 7][8*q];
            hf1.s = *(const s16x8*)&hbuf[cur][c & 7][32 + 8*q];
            f32x4 acc[4];
#pragma unroll
            for (int a = 0; a < 4; ++a) {
                acc[a] = mfma16(hf0.b, wf[a][0].b, gyr[a]);
                acc[a] = mfma16(hf1.b, wf[a][1].b, acc[a]);
            }
            // ---- row self-select: q>=2 lanes' own acc[2],acc[3] ARE rows r0,r0+1
            // (bit-exact duplicates of the q<2 rows; no cross-lane op needed)
            const bool hiq = (q >= 2);
            float g0[4], g1[4];
#pragma unroll
            for (int a = 0; a < 4; ++a) {
                g0[a] = hiq ? acc[a][2] : acc[a][0];
                g1[a] = hiq ? acc[a][3] : acc[a][1];
            }
            const float dn0 = dbuf[t+1][r0 + 0];   // mask for NEXT step
            const float dn1 = dbuf[t+1][r0 + 1];
            // ---- gy[t+1] refill (independent; MFMA pipe hides under ELEM's VALU chain)
            if (t < TT-1) {
                const int tn = t + 1;
                const int ch = (tn >> 3) & 1, sl = tn & 7;
                Frag yc0, yc1;
                yc0.s = *(const s16x8*)&ybuf[ch][sl][((c & 7)*4 + q)*8];
                yc1.s = *(const s16x8*)&ybuf[ch][sl][(32 + (c & 7)*4 + q)*8];
#pragma unroll
                for (int a = 0; a < 4; ++a) {
                    f32x4 g = (f32x4){biasv[a], biasv[a], biasv[a], biasv[a]};
                    g = mfma16(yc0.b, wfi[a][0].b, g);
                    g = mfma16(yc1.b, wfi[a][1].b, g);
                    gyr[a] = g;
                }
            }
            // ---- elementwise, 2 cells/lane (fused-rcp: 5 exp + 3 rcp per cell)
#define ELEM(GV, CSTV, RI, DN) {                                        \
            float ei = __expf(-GV[0]), ef = __expf(-GV[1]);             \
            float eg = __expf(-2.0f*GV[2]), eo = __expf(-GV[3]);        \
            float term = (1.0f - eg) * fast_rcp((1.0f + ei)*(1.0f + eg)); \
            float cn = fast_rcp(1.0f + ef)*CSTV + term;                 \
            float ec = __expf(-2.0f*cn);                                \
            float hv = (1.0f - ec) * fast_rcp((1.0f + eo)*(1.0f + ec)); \
            short zb = f2bf(hv);                                        \
            zbuf[cur][RI][jcol] = zb;                                   \
            const bool d = ((DN) != 0.0f);                              \
            CSTV = d ? 0.0f : cn;                                       \
            hbuf[cur ^ 1][RI][jcol] = d ? (short)0 : zb; }
            ELEM(g0, cst0, r0 + 0, dn0)
            ELEM(g1, cst1, r0 + 1, dn1)
#undef ELEM
        } else {
            // ---- helpers: staging / flush / head
            if ((t & 7) == 0 && t < 120) {        // stage y chunk (t/8)+1
                const int k = (t >> 3) + 1;
#pragma unroll
                for (int i = 0; i < 2; ++i) {
                    const int ss = hw*2 + i;
                    const short* gp = y_sw + ((size_t)(8*k + ss)*256 + blk)*512 + lane*8;
                    GLDS(gp, &ybuf[k & 1][ss][0]);
                }
            }
            if ((t & 7) == 1 && t > 8 && w == 4) { // flush chunk (t/8)-1 outputs
                const int cc = (t >> 3) - 1;
                const int s = lane >> 3, r = lane & 7;
                const size_t row = (size_t)(8*cc + s)*BB + b0 + r;
                const float* ob = &obuf[cc & 1][s][r][0];
                float* lp = out_logits + row*AA;
#pragma unroll
                for (int n = 0; n < 15; ++n) lp[n] = ob[n];
                out_vf[row] = ob[15];
            }
            if (t >= 1 && w == 4 + ((t + 2) & 3)) { // head for z[t-1] (offset avoids flush wave)
                const int tp = t - 1;
                Frag zf0, zf1;
                zf0.s = *(const s16x8*)&zbuf[tp & 1][c & 7][8*q];
                zf1.s = *(const s16x8*)&zbuf[tp & 1][c & 7][32 + 8*q];
                f32x4 ha = (f32x4){hbv, hbv, hbv, hbv};
                ha = mfma16(zf0.b, hwf[0].b, ha);
                ha = mfma16(zf1.b, hwf[1].b, ha);
                if (q < 2) {
#pragma unroll
                    for (int i = 0; i < 4; ++i)
                        obuf[(tp >> 3) & 1][tp & 7][4*q + i][c] = ha[i];
                }
            }
            if ((t & 7) == 6)                      // drain staging off crit path
                __builtin_amdgcn_s_waitcnt(0x0F70);
        }
        block_sync_lds();   // lgkmcnt-only barrier: vmem stays in flight
    }

    // ---------------- epilogue ----------------
    if (!crit && w == 7) {                         // head for z[127]
        Frag zf0, zf1;
        zf0.s = *(const s16x8*)&zbuf[1][c & 7][8*q];
        zf1.s = *(const s16x8*)&zbuf[1][c & 7][32 + 8*q];
        f32x4 ha = (f32x4){hbv, hbv, hbv, hbv};
        ha = mfma16(zf0.b, hwf[0].b, ha);
        ha = mfma16(zf1.b, hwf[1].b, ha);
        if (q < 2) {
#pragma unroll
            for (int i = 0; i < 4; ++i) obuf[1][7][4*q + i][c] = ha[i];
        }
    }
    __syncthreads();
    if (!crit && w == 4) {                         // flush chunk 15
        const int s = lane >> 3, r = lane & 7;
        const size_t row = (size_t)(120 + s)*BB + b0 + r;
        const float* ob = &obuf[1][s][r][0];
        float* lp = out_logits + row*AA;
#pragma unroll
        for (int n = 0; n < 15; ++n) lp[n] = ob[n];
        out_vf[row] = ob[15];
    }
    if (tid < 128) {                               // hT = z127
        int mm = tid & 7, j4 = (tid >> 3) & 15;
        f32x4 hv;
#pragma unroll
        for (int ii = 0; ii < 4; ++ii) hv[ii] = bf2f(zbuf[1][mm][4*j4 + ii]);
        *(f32x4*)(hT_out + (size_t)(b0 + mm)*HH + 4*j4) = hv;
    }
    if (crit) {
        const int jcol = 16*w + c;
        cT_out[(size_t)(b0 + r0 + 0)*HH + jcol] = cst0;
        cT_out[(size_t)(b0 + r0 + 1)*HH + jcol] = cst1;
    }
}

// ============================ launch ============================
extern "C" void kernel_launch(void* const* d_in, const int* in_sizes, int n_in,
                              void* d_out, int out_size, void* d_ws, size_t ws_size,
                              hipStream_t stream) {
    const float* x    = (const float*)d_in[0];
    const float* done = (const float*)d_in[1];
    const float* h0   = (const float*)d_in[2];
    const float* c0   = (const float*)d_in[3];
    const float* W1   = (const float*)d_in[4];
    const float* b1   = (const float*)d_in[5];
    const float* W2   = (const float*)d_in[6];
    const float* b2   = (const float*)d_in[7];
    const float* Wih  = (const float*)d_in[8];
    const float* bih  = (const float*)d_in[9];
    const float* Whh  = (const float*)d_in[10];
    const float* bhh  = (const float*)d_in[11];
    const float* Wa   = (const float*)d_in[12];
    const float* ba   = (const float*)d_in[13];
    const float* Wc   = (const float*)d_in[14];
    const float* bc   = (const float*)d_in[15];
    float* out = (float*)d_out;

    short* y_sw = (short*)d_ws;     // 32 MiB swizzled encoder output (8-row records)

    enc_kernel<<<1024, 256, 0, stream>>>(x, W1, b1, W2, b2, y_sw);
    scan_kernel<<<256, 512, 0, stream>>>(y_sw, done, h0, c0, Wih, bih, Whh, bhh,
                                         Wa, ba, Wc, bc,
                                         out + LOGITS_OFF, out + VF_OFF,
                                         out + HT_OFF, out + CT_OFF);
}